// Round 3
// baseline (5909.108 us; speedup 1.0000x reference)
//
#include <hip/hip_runtime.h>
#include <hip/hip_bf16.h>

// Problem constants (fixed by setup_inputs)
#define BB 2
#define SS 4096
#define DD 256
#define FFD 512
#define NLAYER 4
#define NHEAD 8
#define HD 32
#define QKVD (3*DD)
#define NROWS (BB*SS)   // 8192
#define NCTX 2048       // n_ctx is a fixed scalar input (2048)

// All inputs/outputs are fp32 (reference declares jnp.float32 everywhere; the
// "(bf16, ref=np)" in the harness refers to the comparison precision only).

// ---------- plain fp32 copy (4 elems/thread) ----------
__global__ void copy_kernel(const float* __restrict__ in, float* __restrict__ out, int n) {
    int i = (blockIdx.x * blockDim.x + threadIdx.x) * 4;
    if (i >= n) return;
    *reinterpret_cast<float4*>(out + i) = *reinterpret_cast<const float4*>(in + i);
}

// ---------- LayerNorm: one wave per row of D=256; fp32 in/out ----------
__global__ void ln_kernel(const float* __restrict__ x, const float* __restrict__ w,
                          const float* __restrict__ b, float* __restrict__ out) {
    int row = blockIdx.x * 4 + (threadIdx.x >> 6);
    int lane = threadIdx.x & 63;
    int c = lane * 4;
    float4 v = *reinterpret_cast<const float4*>(x + (size_t)row * DD + c);
    float s  = v.x + v.y + v.z + v.w;
    float sq = v.x*v.x + v.y*v.y + v.z*v.z + v.w*v.w;
    #pragma unroll
    for (int off = 32; off >= 1; off >>= 1) {
        s  += __shfl_xor(s, off);
        sq += __shfl_xor(sq, off);
    }
    float mu   = s * (1.0f / DD);
    float var  = sq * (1.0f / DD) - mu * mu;
    float rstd = rsqrtf(var + 1e-5f);
    float4 wv = *reinterpret_cast<const float4*>(w + c);
    float4 bv = *reinterpret_cast<const float4*>(b + c);
    float4 o;
    o.x = (v.x - mu) * rstd * wv.x + bv.x;
    o.y = (v.y - mu) * rstd * wv.y + bv.y;
    o.z = (v.z - mu) * rstd * wv.z + bv.z;
    o.w = (v.w - mu) * rstd * wv.w + bv.w;
    *reinterpret_cast<float4*>(out + (size_t)row * DD + c) = o;
}

__device__ __forceinline__ float gelu_f(float v) {
    return 0.5f * v * (1.0f + erff(v * 0.70710678118654752f));
}

// ---------- GEMM: out[M,N] = A[M,K] @ W[N,K]^T + bias, tile 16x64, TK=32 ----------
// ACT: 1 = gelu on result. RES: 1 -> out += result (residual, in place).
template<int ACT, int RES>
__global__ void gemm_kernel(const float* __restrict__ A, const float* __restrict__ W,
                            const float* __restrict__ bias, float* __restrict__ out,
                            int N, int K) {
    __shared__ float As[16][33];
    __shared__ float Ws[64][33];
    int tid = threadIdx.x;
    int m0 = blockIdx.y * 16, n0 = blockIdx.x * 64;
    int r = tid >> 4, cg = tid & 15;
    int c4 = cg * 4;
    float a0 = 0.f, a1 = 0.f, a2 = 0.f, a3 = 0.f;
    for (int k0 = 0; k0 < K; k0 += 32) {
        if (tid < 128) {
            int row = tid >> 3, kc = (tid & 7) * 4;
            float4 t = *reinterpret_cast<const float4*>(A + (size_t)(m0 + row) * K + k0 + kc);
            As[row][kc + 0] = t.x; As[row][kc + 1] = t.y;
            As[row][kc + 2] = t.z; As[row][kc + 3] = t.w;
        }
        {
            int row = tid >> 2, kc = (tid & 3) * 8;
            const float* wp = W + (size_t)(n0 + row) * K + k0 + kc;
            float4 t0 = *reinterpret_cast<const float4*>(wp);
            float4 t1 = *reinterpret_cast<const float4*>(wp + 4);
            Ws[row][kc + 0] = t0.x; Ws[row][kc + 1] = t0.y;
            Ws[row][kc + 2] = t0.z; Ws[row][kc + 3] = t0.w;
            Ws[row][kc + 4] = t1.x; Ws[row][kc + 5] = t1.y;
            Ws[row][kc + 6] = t1.z; Ws[row][kc + 7] = t1.w;
        }
        __syncthreads();
        #pragma unroll
        for (int k = 0; k < 32; k++) {
            float av = As[r][k];
            a0 = fmaf(av, Ws[c4 + 0][k], a0);
            a1 = fmaf(av, Ws[c4 + 1][k], a1);
            a2 = fmaf(av, Ws[c4 + 2][k], a2);
            a3 = fmaf(av, Ws[c4 + 3][k], a3);
        }
        __syncthreads();
    }
    int n = n0 + c4;
    float4 bv = *reinterpret_cast<const float4*>(bias + n);
    float v0 = a0 + bv.x;
    float v1 = a1 + bv.y;
    float v2 = a2 + bv.z;
    float v3 = a3 + bv.w;
    if (ACT == 1) { v0 = gelu_f(v0); v1 = gelu_f(v1); v2 = gelu_f(v2); v3 = gelu_f(v3); }
    float* op = out + (size_t)(m0 + r) * N + n;
    if (RES) {
        float4 old = *reinterpret_cast<const float4*>(op);
        v0 += old.x; v1 += old.y; v2 += old.z; v3 += old.w;
    }
    float4 o; o.x = v0; o.y = v1; o.z = v2; o.w = v3;
    *reinterpret_cast<float4*>(op) = o;
}

// ---------- Attention: flash-style, one wave per query, K/V tiles in LDS ----------
#define KT 128
#define NTILE (NCTX / KT)   // 16
#define KSTR 33
__global__ void attn_kernel(const float* __restrict__ qkv, float* __restrict__ out) {
    __shared__ float kS[KT][KSTR];
    __shared__ float vS[KT][KSTR];
    int tid = threadIdx.x;
    int lane = tid & 63;
    int wave = tid >> 6;
    int bh = blockIdx.y;
    int b = bh >> 3;      // NHEAD = 8
    int hh = bh & 7;
    int qi = blockIdx.x * 4 + wave;

    const float* qp = qkv + ((size_t)(b * SS + qi)) * QKVD + hh * HD;
    float q[HD];
    #pragma unroll
    for (int i = 0; i < 8; i++) {
        float4 t = *reinterpret_cast<const float4*>(qp + i * 4);
        q[i*4+0] = t.x; q[i*4+1] = t.y; q[i*4+2] = t.z; q[i*4+3] = t.w;
    }

    float m = -1e30f, l = 0.0f;
    float acc[HD];
    #pragma unroll
    for (int d = 0; d < HD; d++) acc[d] = 0.0f;
    const float scale = 0.17677669529663687f;  // 1/sqrt(32)

    int lrow = tid >> 1;
    int loff = (tid & 1) * 16;
    for (int t = 0; t < NTILE; t++) {
        int k0 = t * KT;
        {
            int gk = k0 + lrow;
            const float* kp = qkv + ((size_t)(b * SS + gk)) * QKVD + DD + hh * HD + loff;
            const float* vp = kp + DD;
            #pragma unroll
            for (int i = 0; i < 4; i++) {
                float4 kv = *reinterpret_cast<const float4*>(kp + i * 4);
                kS[lrow][loff + i*4 + 0] = kv.x; kS[lrow][loff + i*4 + 1] = kv.y;
                kS[lrow][loff + i*4 + 2] = kv.z; kS[lrow][loff + i*4 + 3] = kv.w;
                float4 vv = *reinterpret_cast<const float4*>(vp + i * 4);
                vS[lrow][loff + i*4 + 0] = vv.x; vS[lrow][loff + i*4 + 1] = vv.y;
                vS[lrow][loff + i*4 + 2] = vv.z; vS[lrow][loff + i*4 + 3] = vv.w;
            }
        }
        __syncthreads();
        #pragma unroll
        for (int jj = 0; jj < 2; jj++) {
            int jl = lane + jj * 64;
            const float* kr = kS[jl];
            float s = 0.0f;
            #pragma unroll
            for (int d = 0; d < HD; d++) s = fmaf(q[d], kr[d], s);
            s *= scale;
            float nm = fmaxf(m, s);
            float corr = __expf(m - nm);
            float p = __expf(s - nm);
            l = l * corr + p;
            const float* vr = vS[jl];
            #pragma unroll
            for (int d = 0; d < HD; d++) acc[d] = fmaf(acc[d], corr, p * vr[d]);
            m = nm;
        }
        __syncthreads();
    }

    // merge 64 per-lane online-softmax states
    #pragma unroll
    for (int off = 32; off >= 1; off >>= 1) {
        float m2 = __shfl_xor(m, off);
        float l2 = __shfl_xor(l, off);
        float nm = fmaxf(m, m2);
        float c1 = __expf(m - nm);
        float c2 = __expf(m2 - nm);
        l = l * c1 + l2 * c2;
        #pragma unroll
        for (int d = 0; d < HD; d++) {
            float o2 = __shfl_xor(acc[d], off);
            acc[d] = acc[d] * c1 + o2 * c2;
        }
        m = nm;
    }

    if (lane == 0) {
        float inv = 1.0f / l;
        float* op = out + ((size_t)(b * SS + qi)) * DD + hh * HD;
        #pragma unroll
        for (int i = 0; i < 8; i++) {
            float4 o;
            o.x = acc[i*4+0] * inv; o.y = acc[i*4+1] * inv;
            o.z = acc[i*4+2] * inv; o.w = acc[i*4+3] * inv;
            *reinterpret_cast<float4*>(op + i * 4) = o;
        }
    }
}

extern "C" void kernel_launch(void* const* d_in, const int* in_sizes, int n_in,
                              void* d_out, int out_size, void* d_ws, size_t ws_size,
                              hipStream_t stream) {
    const float* seq   = (const float*)d_in[0];
    const float* Wqkv  = (const float*)d_in[1];
    const float* bqkv  = (const float*)d_in[2];
    const float* Wo    = (const float*)d_in[3];
    const float* bo    = (const float*)d_in[4];
    const float* ln1w  = (const float*)d_in[5];
    const float* ln1b  = (const float*)d_in[6];
    const float* ln2w  = (const float*)d_in[7];
    const float* ln2b  = (const float*)d_in[8];
    const float* W1    = (const float*)d_in[9];
    const float* b1    = (const float*)d_in[10];
    const float* W2    = (const float*)d_in[11];
    const float* b2    = (const float*)d_in[12];
    // d_in[13] = n_ctx (fixed 2048) -- hardcoded as NCTX.

    const int NX = NROWS * DD;                         // 2,097,152
    // Workspace (32 MB): x fp32 [8192,256] @ ws; qkv fp32 [8192,768] @ ws+8MB
    // (ff [8192,512] reuses qkv). h fp32 [8192,256] lives in d_out (8 MB);
    // the final copy overwrites it with the real output last.
    float* x   = (float*)d_ws;
    float* qkv = (float*)d_ws + NX;
    float* ff  = qkv;
    float* h   = (float*)d_out;

    // seq -> residual stream
    copy_kernel<<<NX / (256 * 4), 256, 0, stream>>>(seq, x, NX);

    for (int l = 0; l < NLAYER; l++) {
        const float* wqkv_l = Wqkv + (size_t)l * QKVD * DD;
        const float* bqkv_l = bqkv + (size_t)l * QKVD;
        const float* wo_l   = Wo   + (size_t)l * DD * DD;
        const float* bo_l   = bo   + (size_t)l * DD;
        const float* w1_l   = W1   + (size_t)l * FFD * DD;
        const float* b1_l   = b1   + (size_t)l * FFD;
        const float* w2_l   = W2   + (size_t)l * DD * FFD;
        const float* b2_l   = b2   + (size_t)l * DD;

        // LN1: x -> h
        ln_kernel<<<NROWS / 4, 256, 0, stream>>>(x, ln1w + l * DD, ln1b + l * DD, h);
        // QKV: h -> qkv [8192 x 768]
        gemm_kernel<0, 0><<<dim3(QKVD / 64, NROWS / 16), 256, 0, stream>>>(h, wqkv_l, bqkv_l, qkv, QKVD, DD);
        // attention: qkv -> h
        attn_kernel<<<dim3(SS / 4, BB * NHEAD), 256, 0, stream>>>(qkv, h);
        // out proj + residual: x += h @ Wo^T + bo
        gemm_kernel<0, 1><<<dim3(DD / 64, NROWS / 16), 256, 0, stream>>>(h, wo_l, bo_l, x, DD, DD);
        // LN2: x -> h
        ln_kernel<<<NROWS / 4, 256, 0, stream>>>(x, ln2w + l * DD, ln2b + l * DD, h);
        // FF1 + gelu: h -> ff [8192 x 512]
        gemm_kernel<1, 0><<<dim3(FFD / 64, NROWS / 16), 256, 0, stream>>>(h, w1_l, b1_l, ff, FFD, DD);
        // FF2 + residual: x += ff @ W2^T + b2
        gemm_kernel<0, 1><<<dim3(DD / 64, NROWS / 16), 256, 0, stream>>>(ff, w2_l, b2_l, x, DD, FFD);
    }

    // final: x -> d_out
    copy_kernel<<<NX / (256 * 4), 256, 0, stream>>>(x, (float*)d_out, NX);
}

// Round 4
// 706.984 us; speedup vs baseline: 8.3582x; 8.3582x over previous
//
#include <hip/hip_runtime.h>
#include <hip/hip_bf16.h>

// Problem constants (fixed by setup_inputs)
#define BB 2
#define SS 4096
#define DD 256
#define FFD 512
#define NLAYER 4
#define NHEAD 8
#define HD 32
#define QKVD 768
#define NROWS 8192
#define NCTX 2048       // n_ctx fixed scalar input

typedef unsigned short u16;
typedef unsigned int   u32;
typedef __attribute__((ext_vector_type(8))) short short8;  // 8 bf16 (4 VGPRs)
typedef __attribute__((ext_vector_type(4))) float f32x4;   // MFMA C/D

__device__ __forceinline__ float bf2f(u32 u) { return __uint_as_float(u << 16); }
__device__ __forceinline__ u16 f2bu(float f) {
    union { __hip_bfloat16 h; u16 u; } cv; cv.h = __float2bfloat16(f); return cv.u;
}
__device__ __forceinline__ float gelu_f(float v) {
    return 0.5f * v * (1.0f + erff(v * 0.70710678118654752f));
}

// ---------- fp32 copy ----------
__global__ void copy_kernel(const float* __restrict__ in, float* __restrict__ out, int n) {
    int i = (blockIdx.x * blockDim.x + threadIdx.x) * 4;
    if (i >= n) return;
    *reinterpret_cast<float4*>(out + i) = *reinterpret_cast<const float4*>(in + i);
}

// ---------- fp32 -> bf16 (weights / generic) ----------
__global__ void f2bw_kernel(const float* __restrict__ in, u16* __restrict__ out, int n) {
    int i = (blockIdx.x * blockDim.x + threadIdx.x) * 4;
    if (i >= n) return;
    float4 v = *reinterpret_cast<const float4*>(in + i);
    uint2 o;
    o.x = (u32)f2bu(v.x) | ((u32)f2bu(v.y) << 16);
    o.y = (u32)f2bu(v.z) | ((u32)f2bu(v.w) << 16);
    *reinterpret_cast<uint2*>(out + i) = o;
}

// ---------- LayerNorm: one wave per row (D=256); fp32 in, bf16 out ----------
__global__ void ln_kernel(const float* __restrict__ x, const float* __restrict__ w,
                          const float* __restrict__ b, u16* __restrict__ out) {
    int row = blockIdx.x * 4 + (threadIdx.x >> 6);
    int lane = threadIdx.x & 63;
    int c = lane * 4;
    float4 v = *reinterpret_cast<const float4*>(x + (size_t)row * DD + c);
    float s  = v.x + v.y + v.z + v.w;
    float sq = v.x*v.x + v.y*v.y + v.z*v.z + v.w*v.w;
    #pragma unroll
    for (int off = 32; off >= 1; off >>= 1) {
        s  += __shfl_xor(s, off);
        sq += __shfl_xor(sq, off);
    }
    float mu   = s * (1.0f / DD);
    float var  = sq * (1.0f / DD) - mu * mu;
    float rstd = rsqrtf(var + 1e-5f);
    float4 wv = *reinterpret_cast<const float4*>(w + c);
    float4 bv = *reinterpret_cast<const float4*>(b + c);
    float o0 = (v.x - mu) * rstd * wv.x + bv.x;
    float o1 = (v.y - mu) * rstd * wv.y + bv.y;
    float o2 = (v.z - mu) * rstd * wv.z + bv.z;
    float o3 = (v.w - mu) * rstd * wv.w + bv.w;
    uint2 o;
    o.x = (u32)f2bu(o0) | ((u32)f2bu(o1) << 16);
    o.y = (u32)f2bu(o2) | ((u32)f2bu(o3) << 16);
    *reinterpret_cast<uint2*>(out + (size_t)row * DD + c) = o;
}

// ---------- MFMA GEMM: out[M,N] = A[M,K](bf16) @ W[N,K](bf16)^T + bias ----------
// Tile 128(M)x64(N), BK=32. 4 waves: 2x2, each wave 64x32 via 4x2 16x16 tiles.
// A/B frag layout (verified): lane holds [m|n = lane&15][k = (lane>>4)*8 + j].
// C/D layout (verified): col = lane&15, row = (lane>>4)*4 + reg.
// ACT: 1 = gelu. RES: 1 -> fp32 out += result; RES: 0 -> bf16 store.
template<int ACT, int RES>
__global__ __launch_bounds__(256) void mfma_gemm(
        const u16* __restrict__ A, const u16* __restrict__ W, const float* __restrict__ bias,
        float* __restrict__ outf, u16* __restrict__ outb, int N, int K) {
    __shared__ __align__(16) u16 As[128][40];   // stride 40 elems = 80 B (16B-aligned, conflict-light)
    __shared__ __align__(16) u16 Ws[64][40];
    int tid = threadIdx.x;
    int wave = tid >> 6, lane = tid & 63, la = lane & 15, quad = lane >> 4;
    int wm = (wave & 1) * 64, wn = (wave >> 1) * 32;
    int m0 = blockIdx.y * 128, n0 = blockIdx.x * 64;
    f32x4 acc[4][2];
    #pragma unroll
    for (int mi = 0; mi < 4; mi++)
        #pragma unroll
        for (int ni = 0; ni < 2; ni++)
            acc[mi][ni] = (f32x4){0.f, 0.f, 0.f, 0.f};

    int sr = tid >> 2, sk = (tid & 3) * 8;   // staging: row, k-offset (8 bf16 = 16 B)
    for (int k0 = 0; k0 < K; k0 += 32) {
        *reinterpret_cast<uint4*>(&As[sr][sk]) =
            *reinterpret_cast<const uint4*>(&A[(size_t)(m0 + sr) * K + k0 + sk]);
        *reinterpret_cast<uint4*>(&As[sr + 64][sk]) =
            *reinterpret_cast<const uint4*>(&A[(size_t)(m0 + sr + 64) * K + k0 + sk]);
        *reinterpret_cast<uint4*>(&Ws[sr][sk]) =
            *reinterpret_cast<const uint4*>(&W[(size_t)(n0 + sr) * K + k0 + sk]);
        __syncthreads();
        short8 af[4], bf[2];
        #pragma unroll
        for (int mi = 0; mi < 4; mi++)
            af[mi] = *reinterpret_cast<const short8*>(&As[wm + mi*16 + la][quad*8]);
        #pragma unroll
        for (int ni = 0; ni < 2; ni++)
            bf[ni] = *reinterpret_cast<const short8*>(&Ws[wn + ni*16 + la][quad*8]);
        #pragma unroll
        for (int mi = 0; mi < 4; mi++)
            #pragma unroll
            for (int ni = 0; ni < 2; ni++)
                acc[mi][ni] = __builtin_amdgcn_mfma_f32_16x16x32_bf16(af[mi], bf[ni], acc[mi][ni], 0, 0, 0);
        __syncthreads();
    }

    #pragma unroll
    for (int mi = 0; mi < 4; mi++) {
        #pragma unroll
        for (int ni = 0; ni < 2; ni++) {
            int n = n0 + wn + ni*16 + la;
            float bv = bias[n];
            #pragma unroll
            for (int r = 0; r < 4; r++) {
                int m = m0 + wm + mi*16 + quad*4 + r;
                float v = acc[mi][ni][r] + bv;
                if (ACT) v = gelu_f(v);
                if (RES) outf[(size_t)m * N + n] += v;
                else     outb[(size_t)m * N + n] = f2bu(v);
            }
        }
    }
}

// ---------- MFMA flash attention ----------
// grid (32, 16): x = q-block of 128 (4 waves x 32 q), y = b*8+h.
// K-step = 64 keys staged per block. QK^T: S[32q x 64k] per wave (8 MFMAs).
// Online softmax in C-layout; P -> LDS (bf16, [q][key]); PV as O^T = V^T @ P^T
// (8 MFMAs) so all frag reads are contiguous b128. corr/l broadcast via cbuf.
__global__ __launch_bounds__(256) void mfma_attn(const u16* __restrict__ qkv,
                                                 u16* __restrict__ out) {
    __shared__ __align__(16) u16 Ks[64][40];        // [key][hd]   5120 B
    __shared__ __align__(16) u16 Vt[32][72];        // [hd][key]   4608 B
    __shared__ __align__(16) u16 Ps[4][32][72];     // per-wave P[q][key] 18432 B
    __shared__ float cbuf[4][32];                   // per-wave broadcast (corr / l)

    int tid = threadIdx.x;
    int wv = tid >> 6, lane = tid & 63, la = lane & 15, quad = lane >> 4;
    int bh = blockIdx.y;
    int b = bh >> 3, hh = bh & 7;
    size_t tokbase = (size_t)b * SS;
    int qb = blockIdx.x * 128 + wv * 32;
    const float scale = 0.17677669529663687f;  // 1/sqrt(32)

    // Q frags (A-operand), pre-scaled: lane holds Q[qb+mi*16+la][quad*8 .. +7]
    short8 qf[2];
    #pragma unroll
    for (int mi = 0; mi < 2; mi++) {
        const u16* qp = qkv + (tokbase + qb + mi*16 + la) * QKVD + hh*32 + quad*8;
        uint4 u = *reinterpret_cast<const uint4*>(qp);
        union { short8 v; u16 e[8]; } qa;
        u32 w0 = u.x, w1 = u.y, w2 = u.z, w3 = u.w;
        qa.e[0] = f2bu(bf2f(w0 & 0xffffu) * scale); qa.e[1] = f2bu(bf2f(w0 >> 16) * scale);
        qa.e[2] = f2bu(bf2f(w1 & 0xffffu) * scale); qa.e[3] = f2bu(bf2f(w1 >> 16) * scale);
        qa.e[4] = f2bu(bf2f(w2 & 0xffffu) * scale); qa.e[5] = f2bu(bf2f(w2 >> 16) * scale);
        qa.e[6] = f2bu(bf2f(w3 & 0xffffu) * scale); qa.e[7] = f2bu(bf2f(w3 >> 16) * scale);
        qf[mi] = qa.v;
    }

    f32x4 o[2][2];   // O^T frags: [hd-tile][q-tile]
    #pragma unroll
    for (int i = 0; i < 2; i++)
        #pragma unroll
        for (int j = 0; j < 2; j++) o[i][j] = (f32x4){0.f, 0.f, 0.f, 0.f};
    float m_s[8], l_s[8];   // per (mi, r) rows of this wave's 32 queries
    #pragma unroll
    for (int i = 0; i < 8; i++) { m_s[i] = -1e30f; l_s[i] = 0.0f; }

    int sr = tid >> 2, sk = (tid & 3) * 8;
    for (int step = 0; step < NCTX / 64; step++) {
        int kb = step * 64;
        // stage K [64][hd] and V transposed [hd][64]
        {
            const u16* kp = qkv + (tokbase + kb + sr) * QKVD + DD + hh*32 + sk;
            *reinterpret_cast<uint4*>(&Ks[sr][sk]) = *reinterpret_cast<const uint4*>(kp);
            uint4 vu = *reinterpret_cast<const uint4*>(kp + DD);
            u16 ve[8];
            ve[0] = vu.x & 0xffffu; ve[1] = vu.x >> 16;
            ve[2] = vu.y & 0xffffu; ve[3] = vu.y >> 16;
            ve[4] = vu.z & 0xffffu; ve[5] = vu.z >> 16;
            ve[6] = vu.w & 0xffffu; ve[7] = vu.w >> 16;
            #pragma unroll
            for (int i = 0; i < 8; i++) Vt[sk + i][sr] = ve[i];
        }
        __syncthreads();

        // QK^T -> S (fp32, C-layout)
        short8 kf[4];
        #pragma unroll
        for (int ni = 0; ni < 4; ni++)
            kf[ni] = *reinterpret_cast<const short8*>(&Ks[ni*16 + la][quad*8]);
        f32x4 s[2][4];
        #pragma unroll
        for (int mi = 0; mi < 2; mi++)
            #pragma unroll
            for (int ni = 0; ni < 4; ni++) {
                f32x4 z = (f32x4){0.f, 0.f, 0.f, 0.f};
                s[mi][ni] = __builtin_amdgcn_mfma_f32_16x16x32_bf16(qf[mi], kf[ni], z, 0, 0, 0);
            }

        // online softmax per row (row = mi*16 + quad*4 + r, replicated over la)
        #pragma unroll
        for (int mi = 0; mi < 2; mi++) {
            #pragma unroll
            for (int r = 0; r < 4; r++) {
                float smax = fmaxf(fmaxf(s[mi][0][r], s[mi][1][r]),
                                   fmaxf(s[mi][2][r], s[mi][3][r]));
                #pragma unroll
                for (int off = 1; off < 16; off <<= 1)
                    smax = fmaxf(smax, __shfl_xor(smax, off));
                int idx = mi*4 + r;
                float mnew = fmaxf(m_s[idx], smax);
                float corr = __expf(m_s[idx] - mnew);
                m_s[idx] = mnew;
                float p0 = __expf(s[mi][0][r] - mnew);
                float p1 = __expf(s[mi][1][r] - mnew);
                float p2 = __expf(s[mi][2][r] - mnew);
                float p3 = __expf(s[mi][3][r] - mnew);
                l_s[idx] = l_s[idx] * corr + ((p0 + p1) + (p2 + p3));
                if (la == 0) cbuf[wv][mi*16 + quad*4 + r] = corr;
                int qrow = mi*16 + quad*4 + r;
                Ps[wv][qrow][ 0 + la] = f2bu(p0);
                Ps[wv][qrow][16 + la] = f2bu(p1);
                Ps[wv][qrow][32 + la] = f2bu(p2);
                Ps[wv][qrow][48 + la] = f2bu(p3);
            }
        }
        // rescale O^T by corr(q)  (q = qt*16 + la in O^T layout)
        float c0 = cbuf[wv][la], c1 = cbuf[wv][16 + la];
        #pragma unroll
        for (int mio = 0; mio < 2; mio++)
            #pragma unroll
            for (int r = 0; r < 4; r++) { o[mio][0][r] *= c0; o[mio][1][r] *= c1; }

        // PV: O^T += V^T @ P^T   (A = Vt rows, B = Ps rows; both b128)
        #pragma unroll
        for (int kh = 0; kh < 2; kh++) {
            short8 pf0 = *reinterpret_cast<const short8*>(&Ps[wv][ 0 + la][kh*32 + quad*8]);
            short8 pf1 = *reinterpret_cast<const short8*>(&Ps[wv][16 + la][kh*32 + quad*8]);
            #pragma unroll
            for (int mio = 0; mio < 2; mio++) {
                short8 vf = *reinterpret_cast<const short8*>(&Vt[mio*16 + la][kh*32 + quad*8]);
                o[mio][0] = __builtin_amdgcn_mfma_f32_16x16x32_bf16(vf, pf0, o[mio][0], 0, 0, 0);
                o[mio][1] = __builtin_amdgcn_mfma_f32_16x16x32_bf16(vf, pf1, o[mio][1], 0, 0, 0);
            }
        }
        __syncthreads();
    }

    // finalize: reduce l across la, broadcast 1/l, write O^T as out rows
    #pragma unroll
    for (int i = 0; i < 8; i++) {
        #pragma unroll
        for (int off = 1; off < 16; off <<= 1) l_s[i] += __shfl_xor(l_s[i], off);
    }
    if (la == 0) {
        #pragma unroll
        for (int mi = 0; mi < 2; mi++)
            #pragma unroll
            for (int r = 0; r < 4; r++) cbuf[wv][mi*16 + quad*4 + r] = l_s[mi*4 + r];
    }
    float li0 = 1.0f / cbuf[wv][la], li1 = 1.0f / cbuf[wv][16 + la];
    #pragma unroll
    for (int mio = 0; mio < 2; mio++) {
        #pragma unroll
        for (int qt = 0; qt < 2; qt++) {
            float li = qt ? li1 : li0;
            size_t token = tokbase + qb + qt*16 + la;
            uint2 w;
            w.x = (u32)f2bu(o[mio][qt][0] * li) | ((u32)f2bu(o[mio][qt][1] * li) << 16);
            w.y = (u32)f2bu(o[mio][qt][2] * li) | ((u32)f2bu(o[mio][qt][3] * li) << 16);
            *reinterpret_cast<uint2*>(&out[token * DD + hh*32 + mio*16 + quad*4]) = w;
        }
    }
}

extern "C" void kernel_launch(void* const* d_in, const int* in_sizes, int n_in,
                              void* d_out, int out_size, void* d_ws, size_t ws_size,
                              hipStream_t stream) {
    const float* seq   = (const float*)d_in[0];
    const float* Wqkv  = (const float*)d_in[1];
    const float* bqkv  = (const float*)d_in[2];
    const float* Wo    = (const float*)d_in[3];
    const float* bo    = (const float*)d_in[4];
    const float* ln1w  = (const float*)d_in[5];
    const float* ln1b  = (const float*)d_in[6];
    const float* ln2w  = (const float*)d_in[7];
    const float* ln2b  = (const float*)d_in[8];
    const float* W1    = (const float*)d_in[9];
    const float* b1    = (const float*)d_in[10];
    const float* W2    = (const float*)d_in[11];
    const float* b2    = (const float*)d_in[12];
    // d_in[13] = n_ctx (fixed 2048), hardcoded as NCTX.

    const int NX = NROWS * DD;   // 2,097,152
    // ws layout (29.4 MB):
    //   x    fp32 [8192,256]          @ 0         (8 MB)   residual stream
    //   qkv  bf16 [8192,768]          @ 8 MB      (12.6 MB)  ff [8192,512] reuses it
    //   hln  bf16 [8192,256]          @ 20 MB     (4.2 MB)   LN outputs
    //   wbf  bf16 all weights         @ 24 MB     (4.2 MB)
    // h bf16 [8192,256] lives in d_out (8 MB fp32 region); final copy last.
    char* wsb = (char*)d_ws;
    float* x    = (float*)wsb;
    u16*   qkv  = (u16*)(wsb + 8388608);
    u16*   ff   = qkv;
    u16*   hln  = (u16*)(wsb + 20971520);
    u16*   wbf  = (u16*)(wsb + 25165824);
    u16* wqkv_b = wbf;                  // 786432 elems
    u16* wo_b   = wbf + 786432;         // 262144
    u16* w1_b   = wbf + 1048576;        // 524288
    u16* w2_b   = wbf + 1572864;        // 524288
    u16* h      = (u16*)d_out;

    // weights fp32 -> bf16 (once per launch)
    f2bw_kernel<<<786432/1024, 256, 0, stream>>>(Wqkv, wqkv_b, 786432);
    f2bw_kernel<<<262144/1024, 256, 0, stream>>>(Wo,   wo_b,   262144);
    f2bw_kernel<<<524288/1024, 256, 0, stream>>>(W1,   w1_b,   524288);
    f2bw_kernel<<<524288/1024, 256, 0, stream>>>(W2,   w2_b,   524288);
    // seq -> residual stream
    copy_kernel<<<NX/1024, 256, 0, stream>>>(seq, x, NX);

    for (int l = 0; l < NLAYER; l++) {
        // LN1: x -> hln
        ln_kernel<<<NROWS/4, 256, 0, stream>>>(x, ln1w + l*DD, ln1b + l*DD, hln);
        // QKV: hln -> qkv (bf16)  [8192 x 768]
        mfma_gemm<0,0><<<dim3(QKVD/64, NROWS/128), 256, 0, stream>>>(
            hln, wqkv_b + (size_t)l*QKVD*DD, bqkv + l*QKVD, nullptr, qkv, QKVD, DD);
        // attention: qkv -> h (bf16)
        mfma_attn<<<dim3(SS/128, BB*NHEAD), 256, 0, stream>>>(qkv, h);
        // out proj + residual: x += h @ Wo^T + bo
        mfma_gemm<0,1><<<dim3(DD/64, NROWS/128), 256, 0, stream>>>(
            h, wo_b + (size_t)l*DD*DD, bo + l*DD, x, nullptr, DD, DD);
        // LN2: x -> hln
        ln_kernel<<<NROWS/4, 256, 0, stream>>>(x, ln2w + l*DD, ln2b + l*DD, hln);
        // FF1 + gelu: hln -> ff (bf16) [8192 x 512]
        mfma_gemm<1,0><<<dim3(FFD/64, NROWS/128), 256, 0, stream>>>(
            hln, w1_b + (size_t)l*FFD*DD, b1 + l*FFD, nullptr, ff, FFD, DD);
        // FF2 + residual: x += ff @ W2^T + b2   (K = 512)
        mfma_gemm<0,1><<<dim3(DD/64, NROWS/128), 256, 0, stream>>>(
            ff, w2_b + (size_t)l*DD*FFD, b2 + l*DD, x, nullptr, DD, FFD);
    }

    // final: x -> d_out (fp32)
    copy_kernel<<<NX/1024, 256, 0, stream>>>(x, (float*)d_out, NX);
}

// Round 5
// 562.840 us; speedup vs baseline: 10.4987x; 1.2561x over previous
//
#include <hip/hip_runtime.h>
#include <hip/hip_bf16.h>

// Problem constants (fixed by setup_inputs)
#define BB 2
#define SS 4096
#define DD 256
#define FFD 512
#define NLAYER 4
#define NHEAD 8
#define HD 32
#define QKVD 768
#define NROWS 8192
#define NCTX 2048       // n_ctx fixed scalar input

typedef unsigned short u16;
typedef unsigned int   u32;
typedef __attribute__((ext_vector_type(8))) short short8;  // 8 bf16 (4 VGPRs)
typedef __attribute__((ext_vector_type(4))) short sv4;     // 4 bf16
typedef __attribute__((ext_vector_type(4))) float f32x4;   // MFMA C/D

__device__ __forceinline__ float bf2f(u32 u) { return __uint_as_float(u << 16); }
__device__ __forceinline__ u16 f2bu(float f) {
    union { __hip_bfloat16 h; u16 u; } cv; cv.h = __float2bfloat16(f); return cv.u;
}
__device__ __forceinline__ float gelu_f(float v) {
    return 0.5f * v * (1.0f + erff(v * 0.70710678118654752f));
}

// ---------- fp32 copy ----------
__global__ void copy_kernel(const float* __restrict__ in, float* __restrict__ out, int n) {
    int i = (blockIdx.x * blockDim.x + threadIdx.x) * 4;
    if (i >= n) return;
    *reinterpret_cast<float4*>(out + i) = *reinterpret_cast<const float4*>(in + i);
}

// ---------- fp32 -> bf16 (weights) ----------
__global__ void f2bw_kernel(const float* __restrict__ in, u16* __restrict__ out, int n) {
    int i = (blockIdx.x * blockDim.x + threadIdx.x) * 4;
    if (i >= n) return;
    float4 v = *reinterpret_cast<const float4*>(in + i);
    uint2 o;
    o.x = (u32)f2bu(v.x) | ((u32)f2bu(v.y) << 16);
    o.y = (u32)f2bu(v.z) | ((u32)f2bu(v.w) << 16);
    *reinterpret_cast<uint2*>(out + i) = o;
}

// ---------- LayerNorm: one wave per row (D=256); fp32 in, bf16 out ----------
__global__ void ln_kernel(const float* __restrict__ x, const float* __restrict__ w,
                          const float* __restrict__ b, u16* __restrict__ out) {
    int row = blockIdx.x * 4 + (threadIdx.x >> 6);
    int lane = threadIdx.x & 63;
    int c = lane * 4;
    float4 v = *reinterpret_cast<const float4*>(x + (size_t)row * DD + c);
    float s  = v.x + v.y + v.z + v.w;
    float sq = v.x*v.x + v.y*v.y + v.z*v.z + v.w*v.w;
    #pragma unroll
    for (int off = 32; off >= 1; off >>= 1) {
        s  += __shfl_xor(s, off);
        sq += __shfl_xor(sq, off);
    }
    float mu   = s * (1.0f / DD);
    float var  = sq * (1.0f / DD) - mu * mu;
    float rstd = rsqrtf(var + 1e-5f);
    float4 wv = *reinterpret_cast<const float4*>(w + c);
    float4 bv = *reinterpret_cast<const float4*>(b + c);
    float o0 = (v.x - mu) * rstd * wv.x + bv.x;
    float o1 = (v.y - mu) * rstd * wv.y + bv.y;
    float o2 = (v.z - mu) * rstd * wv.z + bv.z;
    float o3 = (v.w - mu) * rstd * wv.w + bv.w;
    uint2 o;
    o.x = (u32)f2bu(o0) | ((u32)f2bu(o1) << 16);
    o.y = (u32)f2bu(o2) | ((u32)f2bu(o3) << 16);
    *reinterpret_cast<uint2*>(out + (size_t)row * DD + c) = o;
}

// ---------- MFMA GEMM: out[M,N] = A[M,K](bf16) @ W[N,K](bf16)^T + bias ----------
// Tile TM x 128, BK=32. 4 waves 2x2; wave tile (TM/2) x 64.
// A/B frag: lane holds [m|n = lane&15][k = (lane>>4)*8 + j] (verified r4).
// C/D: col = lane&15, row = (lane>>4)*4 + reg (verified r4).
template<int TM, int ACT, int RES>
__global__ __launch_bounds__(256) void mfma_gemm(
        const u16* __restrict__ A, const u16* __restrict__ W, const float* __restrict__ bias,
        float* __restrict__ outf, u16* __restrict__ outb, int N, int K) {
    constexpr int MI = TM / 32;
    __shared__ __align__(16) u16 As[TM][40];
    __shared__ __align__(16) u16 Ws[128][40];
    int tid = threadIdx.x;
    int wave = tid >> 6, lane = tid & 63, la = lane & 15, quad = lane >> 4;
    int wm = (wave & 1) * (TM / 2), wn = (wave >> 1) * 64;
    int m0 = blockIdx.y * TM, n0 = blockIdx.x * 128;
    f32x4 acc[MI][4];
    #pragma unroll
    for (int mi = 0; mi < MI; mi++)
        #pragma unroll
        for (int ni = 0; ni < 4; ni++)
            acc[mi][ni] = (f32x4){0.f, 0.f, 0.f, 0.f};

    int sr = tid >> 2, sk = (tid & 3) * 8;
    for (int k0 = 0; k0 < K; k0 += 32) {
        #pragma unroll
        for (int i = 0; i < TM / 64; i++)
            *reinterpret_cast<uint4*>(&As[sr + i*64][sk]) =
                *reinterpret_cast<const uint4*>(&A[(size_t)(m0 + sr + i*64) * K + k0 + sk]);
        #pragma unroll
        for (int i = 0; i < 2; i++)
            *reinterpret_cast<uint4*>(&Ws[sr + i*64][sk]) =
                *reinterpret_cast<const uint4*>(&W[(size_t)(n0 + sr + i*64) * K + k0 + sk]);
        __syncthreads();
        short8 af[MI], bf[4];
        #pragma unroll
        for (int mi = 0; mi < MI; mi++)
            af[mi] = *reinterpret_cast<const short8*>(&As[wm + mi*16 + la][quad*8]);
        #pragma unroll
        for (int ni = 0; ni < 4; ni++)
            bf[ni] = *reinterpret_cast<const short8*>(&Ws[wn + ni*16 + la][quad*8]);
        #pragma unroll
        for (int mi = 0; mi < MI; mi++)
            #pragma unroll
            for (int ni = 0; ni < 4; ni++)
                acc[mi][ni] = __builtin_amdgcn_mfma_f32_16x16x32_bf16(af[mi], bf[ni], acc[mi][ni], 0, 0, 0);
        __syncthreads();
    }

    #pragma unroll
    for (int mi = 0; mi < MI; mi++) {
        #pragma unroll
        for (int ni = 0; ni < 4; ni++) {
            int n = n0 + wn + ni*16 + la;
            float bv = bias[n];
            #pragma unroll
            for (int r = 0; r < 4; r++) {
                int m = m0 + wm + mi*16 + quad*4 + r;
                float v = acc[mi][ni][r] + bv;
                if (ACT) v = gelu_f(v);
                if (RES) outf[(size_t)m * N + n] += v;
                else     outb[(size_t)m * N + n] = f2bu(v);
            }
        }
    }
}

// ---------- MFMA flash attention (fixed-shift softmax, permuted key layout) ----------
// grid (64, 16): x = q-block of 64 (4 waves x 16 q), y = b*8+h. K-step 64.
// Key permutation pos(key) = (key&15)*4 + (key>>4), applied to BOTH P columns
// and V^T columns -> PV sums over the same permuted k order (result exact).
// Softmax: p = exp(s*scale - 8) (no running max; scores bounded ~|6|); shift
// cancels in o = (sum p v)/(sum p).
#define ASHIFT 8.0f
__global__ __launch_bounds__(256) void mfma_attn(const u16* __restrict__ qkv,
                                                 u16* __restrict__ out) {
    __shared__ __align__(16) u16 Ks[64][40];     // [key][hd]
    __shared__ __align__(16) u16 Vt[32][68];     // [hd][pos]  stride 68: b64-aligned rows
    __shared__ __align__(16) u16 Ps[4][16][72];  // per-wave P[q][pos]
    __shared__ float cbuf[4][16];                // per-wave l broadcast

    int tid = threadIdx.x;
    int wv = tid >> 6, lane = tid & 63, la = lane & 15, quad = lane >> 4;
    int bh = blockIdx.y;
    int b = bh >> 3, hh = bh & 7;
    size_t tokbase = (size_t)b * SS;
    int qb = blockIdx.x * 64 + wv * 16;
    const float scale = 0.17677669529663687f;  // 1/sqrt(32)

    // Q frag (A-operand, raw bf16): lane holds Q[qb+la][quad*8 .. +7]
    short8 qf = *reinterpret_cast<const short8*>(
        &qkv[(tokbase + qb + la) * QKVD + hh*32 + quad*8]);

    f32x4 o[2];   // O^T frags: [hd-tile][q=la]
    o[0] = (f32x4){0.f, 0.f, 0.f, 0.f};
    o[1] = (f32x4){0.f, 0.f, 0.f, 0.f};
    float l_s[4] = {0.f, 0.f, 0.f, 0.f};   // rows quad*4+r

    int sr = tid >> 2, sk = (tid & 3) * 8;
    int pos_w = ((sr & 15) << 2) | (sr >> 4);   // permuted column for key sr
    for (int step = 0; step < NCTX / 64; step++) {
        int kb = step * 64;
        // stage K [key][hd] (b128) and V^T [hd][pos] (permuted scalar scatter)
        const u16* kp = &qkv[(tokbase + kb + sr) * QKVD + DD + hh*32 + sk];
        *reinterpret_cast<uint4*>(&Ks[sr][sk]) = *reinterpret_cast<const uint4*>(kp);
        uint4 vu = *reinterpret_cast<const uint4*>(kp + DD);
        Vt[sk + 0][pos_w] = (u16)(vu.x);        Vt[sk + 1][pos_w] = (u16)(vu.x >> 16);
        Vt[sk + 2][pos_w] = (u16)(vu.y);        Vt[sk + 3][pos_w] = (u16)(vu.y >> 16);
        Vt[sk + 4][pos_w] = (u16)(vu.z);        Vt[sk + 5][pos_w] = (u16)(vu.z >> 16);
        Vt[sk + 6][pos_w] = (u16)(vu.w);        Vt[sk + 7][pos_w] = (u16)(vu.w >> 16);
        __syncthreads();

        // QK^T -> S[16q x 64k] per wave (4 MFMAs)
        short8 kf[4];
        #pragma unroll
        for (int ni = 0; ni < 4; ni++)
            kf[ni] = *reinterpret_cast<const short8*>(&Ks[ni*16 + la][quad*8]);
        f32x4 s[4];
        #pragma unroll
        for (int ni = 0; ni < 4; ni++) {
            f32x4 z = (f32x4){0.f, 0.f, 0.f, 0.f};
            s[ni] = __builtin_amdgcn_mfma_f32_16x16x32_bf16(qf, kf[ni], z, 0, 0, 0);
        }

        // p = exp(s*scale - 8); write P row-chunks packed b64 at pos = la*4 + ni
        #pragma unroll
        for (int r = 0; r < 4; r++) {
            float p0 = __expf(fmaf(s[0][r], scale, -ASHIFT));
            float p1 = __expf(fmaf(s[1][r], scale, -ASHIFT));
            float p2 = __expf(fmaf(s[2][r], scale, -ASHIFT));
            float p3 = __expf(fmaf(s[3][r], scale, -ASHIFT));
            l_s[r] += (p0 + p1) + (p2 + p3);
            uint2 w;
            w.x = (u32)f2bu(p0) | ((u32)f2bu(p1) << 16);
            w.y = (u32)f2bu(p2) | ((u32)f2bu(p3) << 16);
            *reinterpret_cast<uint2*>(&Ps[wv][quad*4 + r][la*4]) = w;
        }

        // PV: O^T += V^T @ P^T over permuted k (same-wave LDS, no barrier needed)
        #pragma unroll
        for (int kh = 0; kh < 2; kh++) {
            short8 pf = *reinterpret_cast<const short8*>(&Ps[wv][la][kh*32 + quad*8]);
            #pragma unroll
            for (int mio = 0; mio < 2; mio++) {
                sv4 lo = *reinterpret_cast<const sv4*>(&Vt[mio*16 + la][kh*32 + quad*8]);
                sv4 hi = *reinterpret_cast<const sv4*>(&Vt[mio*16 + la][kh*32 + quad*8 + 4]);
                short8 vf = __builtin_shufflevector(lo, hi, 0, 1, 2, 3, 4, 5, 6, 7);
                o[mio] = __builtin_amdgcn_mfma_f32_16x16x32_bf16(vf, pf, o[mio], 0, 0, 0);
            }
        }
        __syncthreads();
    }

    // reduce l across the 16-lane groups (rows stay within quad), broadcast 1/l
    #pragma unroll
    for (int r = 0; r < 4; r++) {
        #pragma unroll
        for (int off = 1; off < 16; off <<= 1) l_s[r] += __shfl_xor(l_s[r], off);
    }
    if (la == 0) {
        #pragma unroll
        for (int r = 0; r < 4; r++) cbuf[wv][quad*4 + r] = l_s[r];
    }
    float li = 1.0f / cbuf[wv][la];
    size_t token = tokbase + qb + la;
    #pragma unroll
    for (int mio = 0; mio < 2; mio++) {
        uint2 w;
        w.x = (u32)f2bu(o[mio][0] * li) | ((u32)f2bu(o[mio][1] * li) << 16);
        w.y = (u32)f2bu(o[mio][2] * li) | ((u32)f2bu(o[mio][3] * li) << 16);
        *reinterpret_cast<uint2*>(&out[token * DD + hh*32 + mio*16 + quad*4]) = w;
    }
}

extern "C" void kernel_launch(void* const* d_in, const int* in_sizes, int n_in,
                              void* d_out, int out_size, void* d_ws, size_t ws_size,
                              hipStream_t stream) {
    const float* seq   = (const float*)d_in[0];
    const float* Wqkv  = (const float*)d_in[1];
    const float* bqkv  = (const float*)d_in[2];
    const float* Wo    = (const float*)d_in[3];
    const float* bo    = (const float*)d_in[4];
    const float* ln1w  = (const float*)d_in[5];
    const float* ln1b  = (const float*)d_in[6];
    const float* ln2w  = (const float*)d_in[7];
    const float* ln2b  = (const float*)d_in[8];
    const float* W1    = (const float*)d_in[9];
    const float* b1    = (const float*)d_in[10];
    const float* W2    = (const float*)d_in[11];
    const float* b2    = (const float*)d_in[12];
    // d_in[13] = n_ctx (fixed 2048), hardcoded as NCTX.

    const int NX = NROWS * DD;   // 2,097,152
    // Residual stream x (fp32, 8 MB) lives in d_out -- the final FF2 RMW leaves
    // the answer in place; no final copy. ws layout (25.2 MB):
    //   qkv bf16 [8192,768] @ 0        (12.6 MB)  -- ff [8192,512] reuses it
    //   h   bf16 [8192,256] @ 12.6 MB  (4.2 MB)   attention output
    //   hln bf16 [8192,256] @ 16.8 MB  (4.2 MB)   LN outputs
    //   wbf bf16 weights    @ 21.0 MB  (4.2 MB)
    float* x    = (float*)d_out;
    char* wsb   = (char*)d_ws;
    u16*  qkv   = (u16*)wsb;
    u16*  ff    = qkv;
    u16*  h     = (u16*)(wsb + 12582912);
    u16*  hln   = (u16*)(wsb + 16777216);
    u16*  wbf   = (u16*)(wsb + 20971520);
    u16* wqkv_b = wbf;                  // 786432 elems
    u16* wo_b   = wbf + 786432;         // 262144
    u16* w1_b   = wbf + 1048576;        // 524288
    u16* w2_b   = wbf + 1572864;        // 524288

    f2bw_kernel<<<786432/1024, 256, 0, stream>>>(Wqkv, wqkv_b, 786432);
    f2bw_kernel<<<262144/1024, 256, 0, stream>>>(Wo,   wo_b,   262144);
    f2bw_kernel<<<524288/1024, 256, 0, stream>>>(W1,   w1_b,   524288);
    f2bw_kernel<<<524288/1024, 256, 0, stream>>>(W2,   w2_b,   524288);
    copy_kernel<<<NX/1024, 256, 0, stream>>>(seq, x, NX);

    for (int l = 0; l < NLAYER; l++) {
        // LN1: x -> hln
        ln_kernel<<<NROWS/4, 256, 0, stream>>>(x, ln1w + l*DD, ln1b + l*DD, hln);
        // QKV: hln -> qkv [8192 x 768], K=256
        mfma_gemm<128,0,0><<<dim3(QKVD/128, NROWS/128), 256, 0, stream>>>(
            hln, wqkv_b + (size_t)l*QKVD*DD, bqkv + l*QKVD, nullptr, qkv, QKVD, DD);
        // attention: qkv -> h
        mfma_attn<<<dim3(SS/64, BB*NHEAD), 256, 0, stream>>>(qkv, h);
        // out proj + residual: x += h @ Wo^T + bo  (N=256, K=256)
        mfma_gemm<64,0,1><<<dim3(DD/128, NROWS/64), 256, 0, stream>>>(
            h, wo_b + (size_t)l*DD*DD, bo + l*DD, x, nullptr, DD, DD);
        // LN2: x -> hln
        ln_kernel<<<NROWS/4, 256, 0, stream>>>(x, ln2w + l*DD, ln2b + l*DD, hln);
        // FF1 + gelu: hln -> ff [8192 x 512], K=256
        mfma_gemm<128,1,0><<<dim3(FFD/128, NROWS/128), 256, 0, stream>>>(
            hln, w1_b + (size_t)l*FFD*DD, b1 + l*FFD, nullptr, ff, FFD, DD);
        // FF2 + residual: x += ff @ W2^T + b2  (N=256, K=512)
        mfma_gemm<64,0,1><<<dim3(DD/128, NROWS/64), 256, 0, stream>>>(
            ff, w2_b + (size_t)l*DD*FFD, b2 + l*DD, x, nullptr, DD, FFD);
    }
    // x (== d_out) already holds the final result.
}